// Round 1
// baseline (306.661 us; speedup 1.0000x reference)
//
#include <hip/hip_runtime.h>
#include <math.h>

#define NTOK 8192   // B*S = 4*2048
#define HDIM 2048
#define FDIM 8192
#define NEXP 8

// ---------------- init: zero accumulators, seed ebar with sum_e b2 ----------------
__global__ __launch_bounds__(256) void init_kernel(float* __restrict__ tok,
                                                   float* __restrict__ mid_pre,
                                                   float* __restrict__ ebar,
                                                   const float* __restrict__ b2) {
  const int stride = gridDim.x * blockDim.x;
  const int i0 = blockIdx.x * blockDim.x + threadIdx.x;
  for (int i = i0; i < 16 * HDIM; i += stride) tok[i] = 0.f;
  for (int i = i0; i < 16 * FDIM; i += stride) mid_pre[i] = 0.f;
  for (int i = i0; i < 2 * HDIM; i += stride) {
    int h = i & (HDIM - 1);
    float s = 0.f;
#pragma unroll
    for (int e = 0; e < NEXP; ++e) s += b2[e * HDIM + h];
    ebar[i] = s;
  }
}

// ---------------- router: logits = x@Wr + br, softmax, top-2 ----------------
// wave-per-8-tokens; lanes split H; butterfly reduce; lane 0 does softmax/top2.
__global__ __launch_bounds__(256) void router_kernel(const float* __restrict__ x,
                                                     const float* __restrict__ Wr,
                                                     const float* __restrict__ br,
                                                     float* __restrict__ G,
                                                     int* __restrict__ sel) {
  const int wave = threadIdx.x >> 6;
  const int lane = threadIdx.x & 63;
  const int n0 = (blockIdx.x * 4 + wave) * 8;

  float acc[8][8];
#pragma unroll
  for (int t = 0; t < 8; ++t)
#pragma unroll
    for (int e = 0; e < 8; ++e) acc[t][e] = 0.f;

  for (int j = 0; j < 32; ++j) {
    const int h = lane + (j << 6);
    float4 wa = *(const float4*)(Wr + h * 8);
    float4 wb = *(const float4*)(Wr + h * 8 + 4);
    float w[8] = {wa.x, wa.y, wa.z, wa.w, wb.x, wb.y, wb.z, wb.w};
#pragma unroll
    for (int t = 0; t < 8; ++t) {
      float xv = x[(size_t)(n0 + t) * HDIM + h];
#pragma unroll
      for (int e = 0; e < 8; ++e) acc[t][e] = fmaf(xv, w[e], acc[t][e]);
    }
  }

#pragma unroll
  for (int t = 0; t < 8; ++t)
#pragma unroll
    for (int e = 0; e < 8; ++e) {
      float v = acc[t][e];
      v += __shfl_xor(v, 1, 64);
      v += __shfl_xor(v, 2, 64);
      v += __shfl_xor(v, 4, 64);
      v += __shfl_xor(v, 8, 64);
      v += __shfl_xor(v, 16, 64);
      v += __shfl_xor(v, 32, 64);
      acc[t][e] = v;
    }

  if (lane == 0) {
    float brv[8];
#pragma unroll
    for (int e = 0; e < 8; ++e) brv[e] = br[e];
#pragma unroll
    for (int t = 0; t < 8; ++t) {
      float l[8];
#pragma unroll
      for (int e = 0; e < 8; ++e) l[e] = acc[t][e] + brv[e];
      float m = l[0];
#pragma unroll
      for (int e = 1; e < 8; ++e) m = fmaxf(m, l[e]);
      float s = 0.f;
#pragma unroll
      for (int e = 0; e < 8; ++e) s += expf(l[e] - m);
      // top-2 via running scalars (no runtime-indexed arrays -> stays in regs)
      float best = l[0], second = -3.4e38f;
      int bi = 0, si = 0;
#pragma unroll
      for (int e = 1; e < 8; ++e) {
        float v = l[e];
        if (v > best) { second = best; si = bi; best = v; bi = e; }
        else if (v > second) { second = v; si = e; }
      }
      const int n = n0 + t;
      const float inv = 1.f / s;
      G[n * 2 + 0] = expf(best - m) * inv;
      G[n * 2 + 1] = expf(second - m) * inv;
      sel[n * 2 + 0] = bi;
      sel[n * 2 + 1] = si;
    }
  }
}

// ---------------- tok[e,k,h] = sum over tokens routed to (e,k) of x[n,h] ----------------
// grid (H/256, NTOK/128); block column-owns h, LDS partials per 16 (e,k) slots.
__global__ __launch_bounds__(256) void tok_kernel(const float* __restrict__ x,
                                                  const int* __restrict__ sel,
                                                  float* __restrict__ tok) {
  __shared__ float part[16][256];
  __shared__ int sidx[256];
  const int tid = threadIdx.x;
  const int h0 = blockIdx.x << 8;
  const int n0 = blockIdx.y << 7;  // 128 tokens per block
#pragma unroll
  for (int s = 0; s < 16; ++s) part[s][tid] = 0.f;
  sidx[tid] = sel[(n0 << 1) + tid];
  __syncthreads();
  for (int i = 0; i < 128; ++i) {
    float v = x[(size_t)(n0 + i) * HDIM + h0 + tid];
    int s0 = sidx[2 * i] << 1;            // (e0, k=0)
    int s1 = (sidx[2 * i + 1] << 1) + 1;  // (e1, k=1)
    part[s0][tid] += v;
    part[s1][tid] += v;
  }
  // each thread owns its column -> no sync needed
#pragma unroll
  for (int s = 0; s < 16; ++s) atomicAdd(&tok[s * HDIM + h0 + tid], part[s][tid]);
}

// ---------------- up-proj: mid_pre[e,k,f] += sum_h tok[e,k,h] * W1[e,h,f] ----------------
// grid (F/1024, H/256, E); thread = 1 float4 of f; both k share the W1 load.
__global__ __launch_bounds__(256) void up_kernel(const float* __restrict__ tok,
                                                 const float* __restrict__ W1,
                                                 float* __restrict__ mid_pre) {
  const int e = blockIdx.z;
  const int tid = threadIdx.x;
  const int f = (blockIdx.x << 10) + (tid << 2);
  const int h0 = blockIdx.y << 8;
  __shared__ float t0s[256], t1s[256];
  t0s[tid] = tok[(e * 2 + 0) * HDIM + h0 + tid];
  t1s[tid] = tok[(e * 2 + 1) * HDIM + h0 + tid];
  __syncthreads();
  const float* Wp = W1 + ((size_t)e * HDIM + h0) * FDIM + f;
  float4 a0 = make_float4(0.f, 0.f, 0.f, 0.f), a1 = make_float4(0.f, 0.f, 0.f, 0.f);
#pragma unroll 4
  for (int hh = 0; hh < 256; ++hh) {
    float4 w = *(const float4*)(Wp + (size_t)hh * FDIM);
    float t0 = t0s[hh], t1 = t1s[hh];
    a0.x = fmaf(t0, w.x, a0.x); a0.y = fmaf(t0, w.y, a0.y);
    a0.z = fmaf(t0, w.z, a0.z); a0.w = fmaf(t0, w.w, a0.w);
    a1.x = fmaf(t1, w.x, a1.x); a1.y = fmaf(t1, w.y, a1.y);
    a1.z = fmaf(t1, w.z, a1.z); a1.w = fmaf(t1, w.w, a1.w);
  }
  float* m0 = mid_pre + (e * 2 + 0) * FDIM + f;
  float* m1 = mid_pre + (e * 2 + 1) * FDIM + f;
  atomicAdd(m0 + 0, a0.x); atomicAdd(m0 + 1, a0.y);
  atomicAdd(m0 + 2, a0.z); atomicAdd(m0 + 3, a0.w);
  atomicAdd(m1 + 0, a1.x); atomicAdd(m1 + 1, a1.y);
  atomicAdd(m1 + 2, a1.z); atomicAdd(m1 + 3, a1.w);
}

// ---------------- gelu: mid = gelu_exact(mid_pre + b1) ----------------
__global__ __launch_bounds__(256) void gelu_kernel(const float* __restrict__ mid_pre,
                                                   const float* __restrict__ b1,
                                                   float* __restrict__ mid) {
  const int i = blockIdx.x * 256 + threadIdx.x;  // 16*FDIM = 131072 total
  const int f = i & (FDIM - 1);
  const int e = (i >> 13) >> 1;
  float v = mid_pre[i] + b1[e * FDIM + f];
  mid[i] = 0.5f * v * (1.f + erff(v * 0.70710678118654752f));
}

// ---------------- down-proj + expert-sum: ebar[k,h] += sum_e sum_f mid[e,k,f]*W2[e,f,h] ----
// grid (F/256, H/1024, E); thread = 1 float4 of h; both k share the W2 load.
__global__ __launch_bounds__(256) void down_kernel(const float* __restrict__ mid,
                                                   const float* __restrict__ W2,
                                                   float* __restrict__ ebar) {
  const int e = blockIdx.z;
  const int tid = threadIdx.x;
  const int f0 = blockIdx.x << 8;
  const int h = (blockIdx.y << 10) + (tid << 2);
  __shared__ float m0s[256], m1s[256];
  m0s[tid] = mid[(e * 2 + 0) * FDIM + f0 + tid];
  m1s[tid] = mid[(e * 2 + 1) * FDIM + f0 + tid];
  __syncthreads();
  const float* Wp = W2 + ((size_t)e * FDIM + f0) * HDIM + h;
  float4 a0 = make_float4(0.f, 0.f, 0.f, 0.f), a1 = make_float4(0.f, 0.f, 0.f, 0.f);
#pragma unroll 4
  for (int ff = 0; ff < 256; ++ff) {
    float4 w = *(const float4*)(Wp + (size_t)ff * HDIM);
    float m0 = m0s[ff], m1 = m1s[ff];
    a0.x = fmaf(m0, w.x, a0.x); a0.y = fmaf(m0, w.y, a0.y);
    a0.z = fmaf(m0, w.z, a0.z); a0.w = fmaf(m0, w.w, a0.w);
    a1.x = fmaf(m1, w.x, a1.x); a1.y = fmaf(m1, w.y, a1.y);
    a1.z = fmaf(m1, w.z, a1.z); a1.w = fmaf(m1, w.w, a1.w);
  }
  atomicAdd(&ebar[h + 0], a0.x); atomicAdd(&ebar[h + 1], a0.y);
  atomicAdd(&ebar[h + 2], a0.z); atomicAdd(&ebar[h + 3], a0.w);
  atomicAdd(&ebar[HDIM + h + 0], a1.x); atomicAdd(&ebar[HDIM + h + 1], a1.y);
  atomicAdd(&ebar[HDIM + h + 2], a1.z); atomicAdd(&ebar[HDIM + h + 3], a1.w);
}

// ---------------- combine: y[n,h] = G[n,0]*ebar[0,h] + G[n,1]*ebar[1,h] ----------------
__global__ __launch_bounds__(256) void combine_kernel(const float* __restrict__ G,
                                                      const float* __restrict__ ebar,
                                                      float* __restrict__ y) {
  const int i4 = blockIdx.x * 256 + threadIdx.x;  // NTOK*HDIM/4 = 4194304 total
  const int n = i4 >> 9;           // HDIM/4 = 512 float4 per row
  const int h = (i4 & 511) << 2;
  const float g0 = G[n * 2 + 0], g1 = G[n * 2 + 1];
  float4 e0 = *(const float4*)(ebar + h);
  float4 e1 = *(const float4*)(ebar + HDIM + h);
  float4 r;
  r.x = fmaf(g0, e0.x, g1 * e1.x);
  r.y = fmaf(g0, e0.y, g1 * e1.y);
  r.z = fmaf(g0, e0.z, g1 * e1.z);
  r.w = fmaf(g0, e0.w, g1 * e1.w);
  *(float4*)(y + ((size_t)n << 11) + h) = r;
}

extern "C" void kernel_launch(void* const* d_in, const int* in_sizes, int n_in,
                              void* d_out, int out_size, void* d_ws, size_t ws_size,
                              hipStream_t stream) {
  const float* x  = (const float*)d_in[0];
  const float* Wr = (const float*)d_in[1];
  const float* br = (const float*)d_in[2];
  const float* W1 = (const float*)d_in[3];
  const float* b1 = (const float*)d_in[4];
  const float* W2 = (const float*)d_in[5];
  const float* b2 = (const float*)d_in[6];
  float* y = (float*)d_out;

  char* ws = (char*)d_ws;
  float* G       = (float*)(ws);             // 8192*2 f32   = 64 KB
  int*   sel     = (int*)(ws + 65536);       // 8192*2 i32   = 64 KB
  float* tok     = (float*)(ws + 131072);    // 16*2048 f32  = 128 KB
  float* mid_pre = (float*)(ws + 262144);    // 16*8192 f32  = 512 KB
  float* mid     = (float*)(ws + 786432);    // 16*8192 f32  = 512 KB
  float* ebar    = (float*)(ws + 1310720);   // 2*2048 f32   = 16 KB

  init_kernel<<<256, 256, 0, stream>>>(tok, mid_pre, ebar, b2);
  router_kernel<<<256, 256, 0, stream>>>(x, Wr, br, G, sel);
  tok_kernel<<<dim3(8, 64), 256, 0, stream>>>(x, sel, tok);
  up_kernel<<<dim3(8, 8, 8), 256, 0, stream>>>(tok, W1, mid_pre);
  gelu_kernel<<<512, 256, 0, stream>>>(mid_pre, b1, mid);
  down_kernel<<<dim3(32, 2, 8), 256, 0, stream>>>(mid, W2, ebar);
  combine_kernel<<<16384, 256, 0, stream>>>(G, ebar, y);
}